// Round 1
// 796.478 us; speedup vs baseline: 1.1274x; 1.1274x over previous
//
#include <hip/hip_runtime.h>
#include <hip/hip_bf16.h>
#include <math.h>

// Problem constants
#define N_TOK   2048      // B*L = 32*64
#define HDIM    512
#define HHALF   256       // H/2
#define QDIM    1024      // 2*H
#define KDIM    256
#define HALF    128
#define HEADS   4
#define KNN     32
#define SUB     512
#define NROWS   8192      // N_TOK * HEADS (batchnorm rows)

// ---------------------------------------------------------------------------
// Generic NT GEMM tile: C[m][n] = sum_k A[m][k] * B[n][k] (+bias, relu)
// 64x64 tile, 256 threads, 4x4 microtile, BK=16.
// ---------------------------------------------------------------------------
__device__ __forceinline__ void gemm_tile_nt(
    const float* __restrict__ A, int lda,
    const float* __restrict__ B, int ldb,
    float* __restrict__ C, int ldc,
    int K, const float* __restrict__ bias, bool relu,
    int m0, int n0)
{
    __shared__ float As[16][68];
    __shared__ float Bs[16][68];
    int tid = threadIdx.x;
    int tx = tid & 15;        // n-dir
    int ty = tid >> 4;        // m-dir
    int lr = tid >> 2;        // 0..63: row within tile for loads
    int lc = (tid & 3) * 4;   // 0,4,8,12: k within K-tile for loads

    float acc[4][4] = {};

    for (int k0 = 0; k0 < K; k0 += 16) {
        float4 a = *(const float4*)(A + (size_t)(m0 + lr) * lda + k0 + lc);
        float4 b = *(const float4*)(B + (size_t)(n0 + lr) * ldb + k0 + lc);
        As[lc + 0][lr] = a.x; As[lc + 1][lr] = a.y;
        As[lc + 2][lr] = a.z; As[lc + 3][lr] = a.w;
        Bs[lc + 0][lr] = b.x; Bs[lc + 1][lr] = b.y;
        Bs[lc + 2][lr] = b.z; Bs[lc + 3][lr] = b.w;
        __syncthreads();
#pragma unroll
        for (int k = 0; k < 16; ++k) {
            float4 av = *(const float4*)&As[k][ty * 4];
            float4 bv = *(const float4*)&Bs[k][tx * 4];
            acc[0][0] = fmaf(av.x, bv.x, acc[0][0]);
            acc[0][1] = fmaf(av.x, bv.y, acc[0][1]);
            acc[0][2] = fmaf(av.x, bv.z, acc[0][2]);
            acc[0][3] = fmaf(av.x, bv.w, acc[0][3]);
            acc[1][0] = fmaf(av.y, bv.x, acc[1][0]);
            acc[1][1] = fmaf(av.y, bv.y, acc[1][1]);
            acc[1][2] = fmaf(av.y, bv.z, acc[1][2]);
            acc[1][3] = fmaf(av.y, bv.w, acc[1][3]);
            acc[2][0] = fmaf(av.z, bv.x, acc[2][0]);
            acc[2][1] = fmaf(av.z, bv.y, acc[2][1]);
            acc[2][2] = fmaf(av.z, bv.z, acc[2][2]);
            acc[2][3] = fmaf(av.z, bv.w, acc[2][3]);
            acc[3][0] = fmaf(av.w, bv.x, acc[3][0]);
            acc[3][1] = fmaf(av.w, bv.y, acc[3][1]);
            acc[3][2] = fmaf(av.w, bv.z, acc[3][2]);
            acc[3][3] = fmaf(av.w, bv.w, acc[3][3]);
        }
        __syncthreads();
    }

    // Epilogue
    float4 bb = make_float4(0.f, 0.f, 0.f, 0.f);
    if (bias) {
        bb.x = bias[n0 + tx * 4 + 0];
        bb.y = bias[n0 + tx * 4 + 1];
        bb.z = bias[n0 + tx * 4 + 2];
        bb.w = bias[n0 + tx * 4 + 3];
    }
#pragma unroll
    for (int i = 0; i < 4; ++i) {
        int m = m0 + ty * 4 + i;
        float4 r;
        r.x = acc[i][0] + bb.x;
        r.y = acc[i][1] + bb.y;
        r.z = acc[i][2] + bb.z;
        r.w = acc[i][3] + bb.w;
        if (relu) {
            r.x = fmaxf(r.x, 0.f); r.y = fmaxf(r.y, 0.f);
            r.z = fmaxf(r.z, 0.f); r.w = fmaxf(r.w, 0.f);
        }
        *(float4*)(C + (size_t)m * ldc + n0 + tx * 4) = r;
    }
}

__global__ __launch_bounds__(256) void gemm_nt_kernel(
    const float* __restrict__ A, int lda,
    const float* __restrict__ B, int ldb,
    float* __restrict__ C, int ldc,
    int K, const float* __restrict__ bias, int relu)
{
    gemm_tile_nt(A, lda, B, ldb, C, ldc, K, bias, relu != 0,
                 blockIdx.x * 64, blockIdx.y * 64);
}

// Batched score GEMM: z = head*2 + half
__global__ __launch_bounds__(256) void score_kernel(
    const float* __restrict__ q, const float* __restrict__ keys,
    float* __restrict__ s1, float* __restrict__ s2)
{
    int z = blockIdx.z;
    int hh = z >> 1;
    int half = z & 1;
    const float* A = q + hh * KDIM + half * HALF;    // lda = 1024
    const float* B = keys + (size_t)z * SUB * HALF;  // ldb = 128
    float* C = (half ? s2 : s1) + hh * SUB;          // ldc = HEADS*SUB = 2048
    gemm_tile_nt(A, QDIM, B, HALF, C, HEADS * SUB, HALF, nullptr, false,
                 blockIdx.x * 64, blockIdx.y * 64);
}

// ---------------------------------------------------------------------------
// BatchNorm: stats over flat (8192, 256), deterministic two-stage
// ---------------------------------------------------------------------------
__global__ __launch_bounds__(256) void bnstat_kernel(
    const float* __restrict__ q, float* __restrict__ partial)
{
    int c = threadIdx.x;
    int b = blockIdx.x;                 // 256 blocks, 32 rows each
    const float* base = q + (size_t)b * 32 * KDIM;
    float s = 0.f, s2 = 0.f;
#pragma unroll 8
    for (int r = 0; r < 32; ++r) {
        float v = base[r * KDIM + c];
        s += v;
        s2 = fmaf(v, v, s2);
    }
    partial[b * KDIM + c] = s;
    partial[256 * KDIM + b * KDIM + c] = s2;
}

__global__ __launch_bounds__(256) void bnfinal_kernel(
    const float* __restrict__ partial,
    const float* __restrict__ gamma, const float* __restrict__ beta,
    float* __restrict__ scsh)
{
    int c = threadIdx.x;
    float s = 0.f, s2 = 0.f;
    for (int b = 0; b < 256; ++b) {
        s += partial[b * KDIM + c];
        s2 += partial[256 * KDIM + b * KDIM + c];
    }
    float mean = s * (1.f / (float)NROWS);
    float var = s2 * (1.f / (float)NROWS) - mean * mean;
    float rstd = rsqrtf(var + 1e-5f);
    float sc = rstd * gamma[c];
    scsh[c] = sc;
    scsh[KDIM + c] = beta[c] - mean * sc;
}

__global__ __launch_bounds__(256) void bnapply_kernel(
    float* __restrict__ q, const float* __restrict__ scsh)
{
    int c = threadIdx.x;
    float sc = scsh[c];
    float sh = scsh[KDIM + c];
    size_t base = (size_t)blockIdx.x * 1024 + c;   // 4 flat rows of 256
#pragma unroll
    for (int r = 0; r < 4; ++r) {
        float v = q[base + r * KDIM];
        q[base + r * KDIM] = fmaf(v, sc, sh);
    }
}

// ---------------------------------------------------------------------------
// Top-k via ballot-popcount radix select (no cross-lane swizzles in hot loop).
// 4 tasks per 256-thread block; each wave owns one (n, head) task.
// The 32nd-largest value's exact bit pattern is found by a 32-step binary
// search on the monotone float->uint map; counting uses __ballot + popcount
// (v_cmp + s_bcnt only). Compaction via ballot + mbcnt. Only the SET of
// selected elements matters downstream (softmax + weighted sum are
// permutation-invariant); ties are measure-zero on random data (same caveat
// as the previous extract-max implementation).
// ---------------------------------------------------------------------------
__device__ __forceinline__ unsigned fmap(float f) {
    unsigned u = __float_as_uint(f);
    return (u & 0x80000000u) ? ~u : (u | 0x80000000u);
}

__device__ __forceinline__ int mbcnt64(unsigned long long m) {
    return __builtin_amdgcn_mbcnt_hi((unsigned)(m >> 32),
           __builtin_amdgcn_mbcnt_lo((unsigned)(m & 0xffffffffu), 0));
}

__global__ __launch_bounds__(256) void topk_kernel(
    const float* __restrict__ s1, const float* __restrict__ s2,
    int* __restrict__ out_idx, float* __restrict__ out_w)
{
    int w = threadIdx.x >> 6;            // wave within block: task slot
    int lane = threadIdx.x & 63;
    int task = blockIdx.x * 4 + w;       // n*HEADS + h

    __shared__ float ts1[4][KNN]; __shared__ int ti1[4][KNN];
    __shared__ float ts2[4][KNN]; __shared__ int ti2[4][KNN];
    __shared__ float scv[4][KNN]; __shared__ int scp[4][KNN];

    // Stage 1: top-32 of 512, twice
    for (int src = 0; src < 2; ++src) {
        const float* base = (src ? s2 : s1) + (size_t)task * SUB;
        float v[8]; unsigned u[8];
#pragma unroll
        for (int i = 0; i < 8; ++i) {
            v[i] = base[lane + 64 * i];
            u[i] = fmap(v[i]);
        }
        // Radix threshold search: t ends as the exact 32nd-largest mapped value
        unsigned t = 0u;
        for (int bit = 31; bit >= 0; --bit) {
            unsigned cand = t | (1u << bit);
            int cnt = 0;
#pragma unroll
            for (int i = 0; i < 8; ++i)
                cnt += __popcll(__ballot(u[i] >= cand));
            if (cnt >= KNN) t = cand;
        }
        // Compaction: selected set -> LDS (unsorted; set semantics suffice)
        float* tsv = src ? ts2[w] : ts1[w];
        int*   tsi = src ? ti2[w] : ti1[w];
        int pbase = 0;
#pragma unroll
        for (int i = 0; i < 8; ++i) {
            unsigned long long m = __ballot(u[i] >= t);
            if (u[i] >= t) {
                int pos = pbase + mbcnt64(m);
                if (pos < KNN) { tsv[pos] = v[i]; tsi[pos] = lane + 64 * i; }
            }
            pbase += __popcll(m);
        }
    }
    __syncthreads();

    // Stage 2: top-32 of the 1024 pairwise sums, same radix select
    float cv[16]; unsigned cu[16];
#pragma unroll
    for (int i = 0; i < 16; ++i) {
        int p = lane + 64 * i;
        cv[i] = ts1[w][p >> 5] + ts2[w][p & 31];
        cu[i] = fmap(cv[i]);
    }
    unsigned t2 = 0u;
    for (int bit = 31; bit >= 0; --bit) {
        unsigned cand = t2 | (1u << bit);
        int cnt = 0;
#pragma unroll
        for (int i = 0; i < 16; ++i)
            cnt += __popcll(__ballot(cu[i] >= cand));
        if (cnt >= KNN) t2 = cand;
    }
    int pbase = 0;
#pragma unroll
    for (int i = 0; i < 16; ++i) {
        unsigned long long m = __ballot(cu[i] >= t2);
        if (cu[i] >= t2) {
            int pos = pbase + mbcnt64(m);
            if (pos < KNN) { scv[w][pos] = cv[i]; scp[w][pos] = lane + 64 * i; }
        }
        pbase += __popcll(m);
    }
    __syncthreads();

    // Softmax over the 32 winners (max via 6-step butterfly; lanes >=32 inert)
    float x = (lane < KNN) ? scv[w][lane] : -3.0e38f;
    float mx = x;
#pragma unroll
    for (int off = 32; off; off >>= 1) mx = fmaxf(mx, __shfl_xor(mx, off));
    float e = (lane < KNN) ? expf(x - mx) : 0.f;
    float ssum = e;
#pragma unroll
    for (int off = 32; off; off >>= 1) ssum += __shfl_xor(ssum, off);

    if (lane < KNN) {
        int p = scp[w][lane];
        int i = p >> 5, j = p & 31;
        int gidx = ti1[w][i] * SUB + ti2[w][j];
        int n = task >> 2, h = task & 3;
        out_idx[n * (HEADS * KNN) + h * KNN + lane] = gidx;
        out_w[n * (HEADS * KNN) + h * KNN + lane] = e / ssum;
    }
}

// ---------------------------------------------------------------------------
// Gather: rows[n][:] = sum_k w[n][k] * values[idx[n][k]][:]
// Block per token, 256 threads. float4 loads: 128 lanes cover a full 2 KB row
// per instruction; two k-phases (even/odd) accumulate in parallel and combine
// through LDS. unroll 8 keeps 8 row-loads in flight per thread.
// ---------------------------------------------------------------------------
__global__ __launch_bounds__(256) void gather_kernel(
    const float* __restrict__ values, const int* __restrict__ idx,
    const float* __restrict__ w, float* __restrict__ rows)
{
    int n = blockIdx.x;
    int tid = threadIdx.x;
    int pair = tid >> 7;      // 0/1: which k-parity this half-block handles
    int c4 = tid & 127;       // float4 column
    __shared__ int sidx[HEADS * KNN];
    __shared__ float sw[HEADS * KNN];
    __shared__ float4 tmp[128];
    if (tid < HEADS * KNN) {
        sidx[tid] = idx[n * (HEADS * KNN) + tid];
        sw[tid] = w[n * (HEADS * KNN) + tid];
    }
    __syncthreads();
    const float4* vv = (const float4*)values;
    float4 acc = make_float4(0.f, 0.f, 0.f, 0.f);
#pragma unroll 8
    for (int k = pair; k < HEADS * KNN; k += 2) {
        float4 v = vv[(size_t)sidx[k] * (HDIM / 4) + c4];
        float wk = sw[k];
        acc.x = fmaf(wk, v.x, acc.x);
        acc.y = fmaf(wk, v.y, acc.y);
        acc.z = fmaf(wk, v.z, acc.z);
        acc.w = fmaf(wk, v.w, acc.w);
    }
    if (pair) tmp[c4] = acc;
    __syncthreads();
    if (!pair) {
        float4 o = tmp[c4];
        acc.x += o.x; acc.y += o.y; acc.z += o.z; acc.w += o.w;
        ((float4*)rows)[(size_t)n * (HDIM / 4) + c4] = acc;
    }
}

// out[b][c] = sum_l rows[b*64+l][c]
__global__ __launch_bounds__(512) void reduce_kernel(
    const float* __restrict__ rows, float* __restrict__ out)
{
    int b = blockIdx.x;
    int c = threadIdx.x;
    float s = 0.f;
    for (int l = 0; l < 64; ++l)
        s += rows[(size_t)(b * 64 + l) * HDIM + c];
    out[b * HDIM + c] = s;
}

// ---------------------------------------------------------------------------
extern "C" void kernel_launch(void* const* d_in, const int* in_sizes, int n_in,
                              void* d_out, int out_size, void* d_ws, size_t ws_size,
                              hipStream_t stream)
{
    const float* x      = (const float*)d_in[0];  // (32,64,512)
    const float* w1     = (const float*)d_in[1];  // (256,512)
    const float* b1     = (const float*)d_in[2];  // (256)
    const float* w2     = (const float*)d_in[3];  // (1024,256)
    const float* b2     = (const float*)d_in[4];  // (1024)
    const float* gamma  = (const float*)d_in[5];  // (256)
    const float* beta   = (const float*)d_in[6];  // (256)
    const float* keys   = (const float*)d_in[7];  // (4,2,512,128)
    const float* values = (const float*)d_in[8];  // (262144,512)
    float* out = (float*)d_out;                   // (32,512)

    // Workspace layout (floats). Total ~50.9 MB.
    float* ws = (float*)d_ws;
    float* h       = ws;                        // 2048*256   = 524288
    float* q       = h + N_TOK * HHALF;         // 2048*1024  = 2097152
    float* partial = q + N_TOK * QDIM;          // 2*256*256  = 131072
    float* scsh    = partial + 2 * 256 * KDIM;  // 512
    float* s1      = scsh + 2 * KDIM;           // 2048*4*512 = 4194304
    float* s2      = s1 + (size_t)N_TOK * HEADS * SUB;
    int*   tidx    = (int*)(s2 + (size_t)N_TOK * HEADS * SUB); // 262144 ints
    float* tw      = (float*)(tidx + N_TOK * HEADS * KNN);     // 262144
    float* rows    = tw + N_TOK * HEADS * KNN;  // 2048*512 = 1048576

    // 1) h = relu(x @ w1^T + b1): M=2048, N=256, K=512
    gemm_nt_kernel<<<dim3(N_TOK / 64, HHALF / 64), 256, 0, stream>>>(
        x, HDIM, w1, HDIM, h, HHALF, HDIM, b1, 1);

    // 2) q = h @ w2^T + b2: M=2048, N=1024, K=256
    gemm_nt_kernel<<<dim3(N_TOK / 64, QDIM / 64), 256, 0, stream>>>(
        h, HHALF, w2, HHALF, q, QDIM, HHALF, b2, 0);

    // 3) BatchNorm over flat (8192, 256)
    bnstat_kernel<<<256, 256, 0, stream>>>(q, partial);
    bnfinal_kernel<<<1, 256, 0, stream>>>(partial, gamma, beta, scsh);
    bnapply_kernel<<<N_TOK, 256, 0, stream>>>(q, scsh);

    // 4) Scores: 8 batched NT-GEMMs, M=2048, N=512, K=128
    score_kernel<<<dim3(N_TOK / 64, SUB / 64, HEADS * 2), 256, 0, stream>>>(
        q, keys, s1, s2);

    // 5) Top-k + softmax: radix-select, 4 tasks per block
    topk_kernel<<<N_TOK * HEADS / 4, 256, 0, stream>>>(s1, s2, tidx, tw);

    // 6) Weighted gather from values
    gather_kernel<<<N_TOK, 256, 0, stream>>>(values, tidx, tw, rows);

    // 7) Reduce over L=64
    reduce_kernel<<<32, 512, 0, stream>>>(rows, out);
}

// Round 2
// 772.892 us; speedup vs baseline: 1.1618x; 1.0305x over previous
//
#include <hip/hip_runtime.h>
#include <hip/hip_bf16.h>
#include <math.h>

// Problem constants
#define N_TOK   2048      // B*L = 32*64
#define HDIM    512
#define HHALF   256       // H/2
#define QDIM    1024      // 2*H
#define KDIM    256
#define HALF    128
#define HEADS   4
#define KNN     32
#define SUB     512
#define NROWS   8192      // N_TOK * HEADS (batchnorm rows)

// ---------------------------------------------------------------------------
// Generic NT GEMM tile: C[m][n] = sum_k A[m][k] * B[n][k] (+bias, relu)
// 64x64 tile, 256 threads, 4x4 microtile, BK=16.  (used for fc1 only)
// ---------------------------------------------------------------------------
__device__ __forceinline__ void gemm_tile_nt(
    const float* __restrict__ A, int lda,
    const float* __restrict__ B, int ldb,
    float* __restrict__ C, int ldc,
    int K, const float* __restrict__ bias, bool relu,
    int m0, int n0)
{
    __shared__ float As[16][68];
    __shared__ float Bs[16][68];
    int tid = threadIdx.x;
    int tx = tid & 15;        // n-dir
    int ty = tid >> 4;        // m-dir
    int lr = tid >> 2;        // 0..63: row within tile for loads
    int lc = (tid & 3) * 4;   // 0,4,8,12: k within K-tile for loads

    float acc[4][4] = {};

    for (int k0 = 0; k0 < K; k0 += 16) {
        float4 a = *(const float4*)(A + (size_t)(m0 + lr) * lda + k0 + lc);
        float4 b = *(const float4*)(B + (size_t)(n0 + lr) * ldb + k0 + lc);
        As[lc + 0][lr] = a.x; As[lc + 1][lr] = a.y;
        As[lc + 2][lr] = a.z; As[lc + 3][lr] = a.w;
        Bs[lc + 0][lr] = b.x; Bs[lc + 1][lr] = b.y;
        Bs[lc + 2][lr] = b.z; Bs[lc + 3][lr] = b.w;
        __syncthreads();
#pragma unroll
        for (int k = 0; k < 16; ++k) {
            float4 av = *(const float4*)&As[k][ty * 4];
            float4 bv = *(const float4*)&Bs[k][tx * 4];
            acc[0][0] = fmaf(av.x, bv.x, acc[0][0]);
            acc[0][1] = fmaf(av.x, bv.y, acc[0][1]);
            acc[0][2] = fmaf(av.x, bv.z, acc[0][2]);
            acc[0][3] = fmaf(av.x, bv.w, acc[0][3]);
            acc[1][0] = fmaf(av.y, bv.x, acc[1][0]);
            acc[1][1] = fmaf(av.y, bv.y, acc[1][1]);
            acc[1][2] = fmaf(av.y, bv.z, acc[1][2]);
            acc[1][3] = fmaf(av.y, bv.w, acc[1][3]);
            acc[2][0] = fmaf(av.z, bv.x, acc[2][0]);
            acc[2][1] = fmaf(av.z, bv.y, acc[2][1]);
            acc[2][2] = fmaf(av.z, bv.z, acc[2][2]);
            acc[2][3] = fmaf(av.z, bv.w, acc[2][3]);
            acc[3][0] = fmaf(av.w, bv.x, acc[3][0]);
            acc[3][1] = fmaf(av.w, bv.y, acc[3][1]);
            acc[3][2] = fmaf(av.w, bv.z, acc[3][2]);
            acc[3][3] = fmaf(av.w, bv.w, acc[3][3]);
        }
        __syncthreads();
    }

    float4 bb = make_float4(0.f, 0.f, 0.f, 0.f);
    if (bias) {
        bb.x = bias[n0 + tx * 4 + 0];
        bb.y = bias[n0 + tx * 4 + 1];
        bb.z = bias[n0 + tx * 4 + 2];
        bb.w = bias[n0 + tx * 4 + 3];
    }
#pragma unroll
    for (int i = 0; i < 4; ++i) {
        int m = m0 + ty * 4 + i;
        float4 r;
        r.x = acc[i][0] + bb.x;
        r.y = acc[i][1] + bb.y;
        r.z = acc[i][2] + bb.z;
        r.w = acc[i][3] + bb.w;
        if (relu) {
            r.x = fmaxf(r.x, 0.f); r.y = fmaxf(r.y, 0.f);
            r.z = fmaxf(r.z, 0.f); r.w = fmaxf(r.w, 0.f);
        }
        *(float4*)(C + (size_t)m * ldc + n0 + tx * 4) = r;
    }
}

__global__ __launch_bounds__(256) void gemm_nt_kernel(
    const float* __restrict__ A, int lda,
    const float* __restrict__ B, int ldb,
    float* __restrict__ C, int ldc,
    int K, const float* __restrict__ bias, int relu)
{
    gemm_tile_nt(A, lda, B, ldb, C, ldc, K, bias, relu != 0,
                 blockIdx.x * 64, blockIdx.y * 64);
}

// ---------------------------------------------------------------------------
// fc2 + fused batchnorm statistics.
// q = h @ w2^T + b2 (64x64 tiles), plus deterministic per-block column
// sums/sumsq written to pstat[2][32][1024] for bnfinal.
// ---------------------------------------------------------------------------
__global__ __launch_bounds__(256) void fc2_stats_kernel(
    const float* __restrict__ A,   // h: 2048 x 256
    const float* __restrict__ B,   // w2: 1024 x 256
    float* __restrict__ C,         // q: 2048 x 1024
    const float* __restrict__ bias,
    float* __restrict__ pstat)     // 2 * 32 * 1024 floats
{
    __shared__ float As[16][68];
    __shared__ float Bs[16][68];
    int tid = threadIdx.x;
    int tx = tid & 15;
    int ty = tid >> 4;
    int lr = tid >> 2;
    int lc = (tid & 3) * 4;
    int m0 = blockIdx.x * 64;   // token block (0..31)
    int n0 = blockIdx.y * 64;   // q-col block (0..15)

    float acc[4][4] = {};

    for (int k0 = 0; k0 < HHALF; k0 += 16) {
        float4 a = *(const float4*)(A + (size_t)(m0 + lr) * HHALF + k0 + lc);
        float4 b = *(const float4*)(B + (size_t)(n0 + lr) * HHALF + k0 + lc);
        As[lc + 0][lr] = a.x; As[lc + 1][lr] = a.y;
        As[lc + 2][lr] = a.z; As[lc + 3][lr] = a.w;
        Bs[lc + 0][lr] = b.x; Bs[lc + 1][lr] = b.y;
        Bs[lc + 2][lr] = b.z; Bs[lc + 3][lr] = b.w;
        __syncthreads();
#pragma unroll
        for (int k = 0; k < 16; ++k) {
            float4 av = *(const float4*)&As[k][ty * 4];
            float4 bv = *(const float4*)&Bs[k][tx * 4];
            acc[0][0] = fmaf(av.x, bv.x, acc[0][0]);
            acc[0][1] = fmaf(av.x, bv.y, acc[0][1]);
            acc[0][2] = fmaf(av.x, bv.z, acc[0][2]);
            acc[0][3] = fmaf(av.x, bv.w, acc[0][3]);
            acc[1][0] = fmaf(av.y, bv.x, acc[1][0]);
            acc[1][1] = fmaf(av.y, bv.y, acc[1][1]);
            acc[1][2] = fmaf(av.y, bv.z, acc[1][2]);
            acc[1][3] = fmaf(av.y, bv.w, acc[1][3]);
            acc[2][0] = fmaf(av.z, bv.x, acc[2][0]);
            acc[2][1] = fmaf(av.z, bv.y, acc[2][1]);
            acc[2][2] = fmaf(av.z, bv.z, acc[2][2]);
            acc[2][3] = fmaf(av.z, bv.w, acc[2][3]);
            acc[3][0] = fmaf(av.w, bv.x, acc[3][0]);
            acc[3][1] = fmaf(av.w, bv.y, acc[3][1]);
            acc[3][2] = fmaf(av.w, bv.z, acc[3][2]);
            acc[3][3] = fmaf(av.w, bv.w, acc[3][3]);
        }
        __syncthreads();
    }

    float4 bb;
    bb.x = bias[n0 + tx * 4 + 0];
    bb.y = bias[n0 + tx * 4 + 1];
    bb.z = bias[n0 + tx * 4 + 2];
    bb.w = bias[n0 + tx * 4 + 3];
    float4 cs  = make_float4(0.f, 0.f, 0.f, 0.f);
    float4 csq = make_float4(0.f, 0.f, 0.f, 0.f);
#pragma unroll
    for (int i = 0; i < 4; ++i) {
        int m = m0 + ty * 4 + i;
        float4 r;
        r.x = acc[i][0] + bb.x;
        r.y = acc[i][1] + bb.y;
        r.z = acc[i][2] + bb.z;
        r.w = acc[i][3] + bb.w;
        *(float4*)(C + (size_t)m * QDIM + n0 + tx * 4) = r;
        cs.x += r.x; cs.y += r.y; cs.z += r.z; cs.w += r.w;
        csq.x = fmaf(r.x, r.x, csq.x);
        csq.y = fmaf(r.y, r.y, csq.y);
        csq.z = fmaf(r.z, r.z, csq.z);
        csq.w = fmaf(r.w, r.w, csq.w);
    }
    // Deterministic column reduction over ty via LDS (reuse As/Bs).
    __syncthreads();
    As[ty][tx * 4 + 0] = cs.x;  As[ty][tx * 4 + 1] = cs.y;
    As[ty][tx * 4 + 2] = cs.z;  As[ty][tx * 4 + 3] = cs.w;
    Bs[ty][tx * 4 + 0] = csq.x; Bs[ty][tx * 4 + 1] = csq.y;
    Bs[ty][tx * 4 + 2] = csq.z; Bs[ty][tx * 4 + 3] = csq.w;
    __syncthreads();
    if (tid < 64) {
        float s = 0.f, s2 = 0.f;
#pragma unroll
        for (int t = 0; t < 16; ++t) { s += As[t][tid]; s2 += Bs[t][tid]; }
        int mb = blockIdx.x;
        pstat[mb * QDIM + n0 + tid] = s;
        pstat[32 * QDIM + mb * QDIM + n0 + tid] = s2;
    }
}

// scsh[c] = rstd*gamma (scale), scsh[256+c] = beta - mean*scale (shift)
__global__ __launch_bounds__(256) void bnfinal_kernel(
    const float* __restrict__ pstat,
    const float* __restrict__ gamma, const float* __restrict__ beta,
    float* __restrict__ scsh)
{
    int c = threadIdx.x;   // 0..255 within KDIM
    float s = 0.f, s2 = 0.f;
    for (int mb = 0; mb < 32; ++mb) {
#pragma unroll
        for (int hd = 0; hd < 4; ++hd) {
            s  += pstat[mb * QDIM + hd * KDIM + c];
            s2 += pstat[32 * QDIM + mb * QDIM + hd * KDIM + c];
        }
    }
    float mean = s * (1.f / (float)NROWS);
    float var = s2 * (1.f / (float)NROWS) - mean * mean;
    float rstd = rsqrtf(var + 1e-5f);
    float sc = rstd * gamma[c];
    scsh[c] = sc;
    scsh[KDIM + c] = beta[c] - mean * sc;
}

// ---------------------------------------------------------------------------
// Fold batchnorm into keys:  s = q·(sc*key) + Σ_d sh_d*key_d
// keys2[z][k][d] = keys[z][k][d]*sc[c],  bias2[z][k] = Σ_d sh[c]*keys[z][k][d]
// where c = (z&1)*128 + d.
// ---------------------------------------------------------------------------
__global__ __launch_bounds__(256) void prep_keys_kernel(
    const float* __restrict__ keys, const float* __restrict__ scsh,
    float* __restrict__ keys2, float* __restrict__ bias2)
{
    int z = blockIdx.x;       // 0..7 (head*2+half)
    int kg = blockIdx.y;      // 0..7
    int half = z & 1;
    int tid = threadIdx.x;
    int r = kg * 64 + (tid >> 2);   // subkey row
    int d0 = (tid & 3) * 32;        // 32 floats per thread
    const float* src = keys  + ((size_t)z * SUB + r) * HALF + d0;
    float*       dst = keys2 + ((size_t)z * SUB + r) * HALF + d0;
    const float* sc = scsh + half * HALF + d0;
    const float* sh = scsh + KDIM + half * HALF + d0;
    float part = 0.f;
#pragma unroll
    for (int j = 0; j < 32; j += 4) {
        float4 kv = *(const float4*)(src + j);
        float4 scv = *(const float4*)(sc + j);
        float4 shv = *(const float4*)(sh + j);
        float4 o;
        o.x = kv.x * scv.x; o.y = kv.y * scv.y;
        o.z = kv.z * scv.z; o.w = kv.w * scv.w;
        part += kv.x * shv.x + kv.y * shv.y + kv.z * shv.z + kv.w * shv.w;
        *(float4*)(dst + j) = o;
    }
    part += __shfl_xor(part, 1);
    part += __shfl_xor(part, 2);
    if ((tid & 3) == 0) bias2[z * SUB + r] = part;
}

// ---------------------------------------------------------------------------
// Score GEMM: 128x128 tile, 8x8 microtile, BK=16, K=128.
// s_half[n][k] = sum_d q[n][qoff+d] * keys2[z][k][d] + bias2[z][k]
// ---------------------------------------------------------------------------
__global__ __launch_bounds__(256) void score128_kernel(
    const float* __restrict__ q, const float* __restrict__ keys2,
    const float* __restrict__ bias2,
    float* __restrict__ s1, float* __restrict__ s2)
{
    int z = blockIdx.z;
    int hh = z >> 1;
    int half = z & 1;
    const float* A = q + hh * KDIM + half * HALF;        // lda = 1024
    const float* B = keys2 + (size_t)z * SUB * HALF;     // ldb = 128
    float* C = (half ? s2 : s1) + hh * SUB;              // ldc = 2048
    int m0 = blockIdx.x * 128;
    int n0 = blockIdx.y * 128;

    __shared__ float As[16][132];
    __shared__ float Bs[16][132];
    int tid = threadIdx.x;
    int tx = tid & 15;        // n-dir: cols tx*8..+7
    int ty = tid >> 4;        // m-dir: rows ty*8..+7
    int lr = tid >> 1;        // 0..127: tile row for staging
    int lc = (tid & 1) * 8;   // 0 or 8: k offset for staging

    float acc[8][8] = {};

#pragma unroll 1
    for (int k0 = 0; k0 < HALF; k0 += 16) {
        float4 a0 = *(const float4*)(A + (size_t)(m0 + lr) * QDIM + k0 + lc);
        float4 a1 = *(const float4*)(A + (size_t)(m0 + lr) * QDIM + k0 + lc + 4);
        float4 b0 = *(const float4*)(B + (size_t)(n0 + lr) * HALF + k0 + lc);
        float4 b1 = *(const float4*)(B + (size_t)(n0 + lr) * HALF + k0 + lc + 4);
        As[lc + 0][lr] = a0.x; As[lc + 1][lr] = a0.y;
        As[lc + 2][lr] = a0.z; As[lc + 3][lr] = a0.w;
        As[lc + 4][lr] = a1.x; As[lc + 5][lr] = a1.y;
        As[lc + 6][lr] = a1.z; As[lc + 7][lr] = a1.w;
        Bs[lc + 0][lr] = b0.x; Bs[lc + 1][lr] = b0.y;
        Bs[lc + 2][lr] = b0.z; Bs[lc + 3][lr] = b0.w;
        Bs[lc + 4][lr] = b1.x; Bs[lc + 5][lr] = b1.y;
        Bs[lc + 6][lr] = b1.z; Bs[lc + 7][lr] = b1.w;
        __syncthreads();
#pragma unroll
        for (int k = 0; k < 16; ++k) {
            float4 av0 = *(const float4*)&As[k][ty * 8];
            float4 av1 = *(const float4*)&As[k][ty * 8 + 4];
            float4 bv0 = *(const float4*)&Bs[k][tx * 8];
            float4 bv1 = *(const float4*)&Bs[k][tx * 8 + 4];
            float a8[8] = {av0.x, av0.y, av0.z, av0.w, av1.x, av1.y, av1.z, av1.w};
            float b8[8] = {bv0.x, bv0.y, bv0.z, bv0.w, bv1.x, bv1.y, bv1.z, bv1.w};
#pragma unroll
            for (int i = 0; i < 8; ++i)
#pragma unroll
                for (int j = 0; j < 8; ++j)
                    acc[i][j] = fmaf(a8[i], b8[j], acc[i][j]);
        }
        __syncthreads();
    }

    float4 sb0 = *(const float4*)(bias2 + z * SUB + n0 + tx * 8);
    float4 sb1 = *(const float4*)(bias2 + z * SUB + n0 + tx * 8 + 4);
#pragma unroll
    for (int i = 0; i < 8; ++i) {
        int m = m0 + ty * 8 + i;
        float4 r0, r1;
        r0.x = acc[i][0] + sb0.x; r0.y = acc[i][1] + sb0.y;
        r0.z = acc[i][2] + sb0.z; r0.w = acc[i][3] + sb0.w;
        r1.x = acc[i][4] + sb1.x; r1.y = acc[i][5] + sb1.y;
        r1.z = acc[i][6] + sb1.z; r1.w = acc[i][7] + sb1.w;
        *(float4*)(C + (size_t)m * (HEADS * SUB) + n0 + tx * 8) = r0;
        *(float4*)(C + (size_t)m * (HEADS * SUB) + n0 + tx * 8 + 4) = r1;
    }
}

// ---------------------------------------------------------------------------
// Top-k via ballot-popcount radix select with exact-count early exit.
// 4 tasks per 256-thread block; each wave owns one (n, head) task.
// ---------------------------------------------------------------------------
__device__ __forceinline__ unsigned fmap(float f) {
    unsigned u = __float_as_uint(f);
    return (u & 0x80000000u) ? ~u : (u | 0x80000000u);
}

__device__ __forceinline__ int mbcnt64(unsigned long long m) {
    return __builtin_amdgcn_mbcnt_hi((unsigned)(m >> 32),
           __builtin_amdgcn_mbcnt_lo((unsigned)(m & 0xffffffffu), 0));
}

__global__ __launch_bounds__(256) void topk_kernel(
    const float* __restrict__ s1, const float* __restrict__ s2,
    int* __restrict__ out_idx, float* __restrict__ out_w)
{
    int w = threadIdx.x >> 6;            // wave within block: task slot
    int lane = threadIdx.x & 63;
    int task = blockIdx.x * 4 + w;       // n*HEADS + h

    __shared__ float ts1[4][KNN]; __shared__ int ti1[4][KNN];
    __shared__ float ts2[4][KNN]; __shared__ int ti2[4][KNN];
    __shared__ float scv[4][KNN]; __shared__ int scp[4][KNN];

    // Stage 1: top-32 of 512, twice
    for (int src = 0; src < 2; ++src) {
        const float* base = (src ? s2 : s1) + (size_t)task * SUB;
        float v[8]; unsigned u[8];
#pragma unroll
        for (int i = 0; i < 8; ++i) {
            v[i] = base[lane + 64 * i];
            u[i] = fmap(v[i]);
        }
        unsigned t = 0u;
        for (int bit = 31; bit >= 0; --bit) {
            unsigned cand = t | (1u << bit);
            int cnt = 0;
#pragma unroll
            for (int i = 0; i < 8; ++i)
                cnt += __popcll(__ballot(u[i] >= cand));
            if (cnt == KNN) { t = cand; break; }   // exact set found
            if (cnt > KNN) t = cand;
        }
        float* tsv = src ? ts2[w] : ts1[w];
        int*   tsi = src ? ti2[w] : ti1[w];
        int pbase = 0;
#pragma unroll
        for (int i = 0; i < 8; ++i) {
            unsigned long long m = __ballot(u[i] >= t);
            if (u[i] >= t) {
                int pos = pbase + mbcnt64(m);
                if (pos < KNN) { tsv[pos] = v[i]; tsi[pos] = lane + 64 * i; }
            }
            pbase += __popcll(m);
        }
    }
    __syncthreads();

    // Stage 2: top-32 of the 1024 pairwise sums
    float cv[16]; unsigned cu[16];
#pragma unroll
    for (int i = 0; i < 16; ++i) {
        int p = lane + 64 * i;
        cv[i] = ts1[w][p >> 5] + ts2[w][p & 31];
        cu[i] = fmap(cv[i]);
    }
    unsigned t2 = 0u;
    for (int bit = 31; bit >= 0; --bit) {
        unsigned cand = t2 | (1u << bit);
        int cnt = 0;
#pragma unroll
        for (int i = 0; i < 16; ++i)
            cnt += __popcll(__ballot(cu[i] >= cand));
        if (cnt == KNN) { t2 = cand; break; }
        if (cnt > KNN) t2 = cand;
    }
    int pbase = 0;
#pragma unroll
    for (int i = 0; i < 16; ++i) {
        unsigned long long m = __ballot(cu[i] >= t2);
        if (cu[i] >= t2) {
            int pos = pbase + mbcnt64(m);
            if (pos < KNN) { scv[w][pos] = cv[i]; scp[w][pos] = lane + 64 * i; }
        }
        pbase += __popcll(m);
    }
    __syncthreads();

    // Softmax over the 32 winners
    float x = (lane < KNN) ? scv[w][lane] : -3.0e38f;
    float mx = x;
#pragma unroll
    for (int off = 32; off; off >>= 1) mx = fmaxf(mx, __shfl_xor(mx, off));
    float e = (lane < KNN) ? expf(x - mx) : 0.f;
    float ssum = e;
#pragma unroll
    for (int off = 32; off; off >>= 1) ssum += __shfl_xor(ssum, off);

    if (lane < KNN) {
        int p = scp[w][lane];
        int i = p >> 5, j = p & 31;
        int gidx = ti1[w][i] * SUB + ti2[w][j];
        int n = task >> 2, h = task & 3;
        out_idx[n * (HEADS * KNN) + h * KNN + lane] = gidx;
        out_w[n * (HEADS * KNN) + h * KNN + lane] = e / ssum;
    }
}

// ---------------------------------------------------------------------------
// Gather: rows[n][:] = sum_k w[n][k] * values[idx[n][k]][:]
// ---------------------------------------------------------------------------
__global__ __launch_bounds__(256) void gather_kernel(
    const float* __restrict__ values, const int* __restrict__ idx,
    const float* __restrict__ w, float* __restrict__ rows)
{
    int n = blockIdx.x;
    int tid = threadIdx.x;
    int pair = tid >> 7;      // 0/1: k-parity
    int c4 = tid & 127;       // float4 column
    __shared__ int sidx[HEADS * KNN];
    __shared__ float sw[HEADS * KNN];
    __shared__ float4 tmp[128];
    if (tid < HEADS * KNN) {
        sidx[tid] = idx[n * (HEADS * KNN) + tid];
        sw[tid] = w[n * (HEADS * KNN) + tid];
    }
    __syncthreads();
    const float4* vv = (const float4*)values;
    float4 acc = make_float4(0.f, 0.f, 0.f, 0.f);
#pragma unroll 8
    for (int k = pair; k < HEADS * KNN; k += 2) {
        float4 v = vv[(size_t)sidx[k] * (HDIM / 4) + c4];
        float wk = sw[k];
        acc.x = fmaf(wk, v.x, acc.x);
        acc.y = fmaf(wk, v.y, acc.y);
        acc.z = fmaf(wk, v.z, acc.z);
        acc.w = fmaf(wk, v.w, acc.w);
    }
    if (pair) tmp[c4] = acc;
    __syncthreads();
    if (!pair) {
        float4 o = tmp[c4];
        acc.x += o.x; acc.y += o.y; acc.z += o.z; acc.w += o.w;
        ((float4*)rows)[(size_t)n * (HDIM / 4) + c4] = acc;
    }
}

// out[b][c] = sum_l rows[b*64+l][c]
__global__ __launch_bounds__(512) void reduce_kernel(
    const float* __restrict__ rows, float* __restrict__ out)
{
    int b = blockIdx.x;
    int c = threadIdx.x;
    float s = 0.f;
    for (int l = 0; l < 64; ++l)
        s += rows[(size_t)(b * 64 + l) * HDIM + c];
    out[b * HDIM + c] = s;
}

// ---------------------------------------------------------------------------
extern "C" void kernel_launch(void* const* d_in, const int* in_sizes, int n_in,
                              void* d_out, int out_size, void* d_ws, size_t ws_size,
                              hipStream_t stream)
{
    const float* x      = (const float*)d_in[0];  // (32,64,512)
    const float* w1     = (const float*)d_in[1];  // (256,512)
    const float* b1     = (const float*)d_in[2];  // (256)
    const float* w2     = (const float*)d_in[3];  // (1024,256)
    const float* b2     = (const float*)d_in[4];  // (1024)
    const float* gamma  = (const float*)d_in[5];  // (256)
    const float* beta   = (const float*)d_in[6];  // (256)
    const float* keys   = (const float*)d_in[7];  // (4,2,512,128)
    const float* values = (const float*)d_in[8];  // (262144,512)
    float* out = (float*)d_out;                   // (32,512)

    // Workspace layout (floats). Total ~53 MB.
    float* ws = (float*)d_ws;
    float* h     = ws;                          // 2048*256
    float* q     = h + N_TOK * HHALF;           // 2048*1024
    float* pstat = q + N_TOK * QDIM;            // 2*32*1024
    float* scsh  = pstat + 2 * 32 * QDIM;       // 512
    float* keys2 = scsh + 2 * KDIM;             // 8*512*128
    float* bias2 = keys2 + 8 * SUB * HALF;      // 8*512
    float* s1    = bias2 + 8 * SUB;             // 2048*4*512
    float* s2    = s1 + (size_t)N_TOK * HEADS * SUB;
    int*   tidx  = (int*)(s2 + (size_t)N_TOK * HEADS * SUB);
    float* tw    = (float*)(tidx + N_TOK * HEADS * KNN);
    float* rows  = tw + N_TOK * HEADS * KNN;    // 2048*512

    // 1) h = relu(x @ w1^T + b1): M=2048, N=256, K=512
    gemm_nt_kernel<<<dim3(N_TOK / 64, HHALF / 64), 256, 0, stream>>>(
        x, HDIM, w1, HDIM, h, HHALF, HDIM, b1, 1);

    // 2) q = h @ w2^T + b2, fused column stats
    fc2_stats_kernel<<<dim3(N_TOK / 64, QDIM / 64), 256, 0, stream>>>(
        h, w2, q, b2, pstat);

    // 3) BatchNorm finalize -> scale/shift
    bnfinal_kernel<<<1, 256, 0, stream>>>(pstat, gamma, beta, scsh);

    // 4) Fold BN into keys: keys2 = keys*sc, bias2 = sh . key
    prep_keys_kernel<<<dim3(8, 8), 256, 0, stream>>>(keys, scsh, keys2, bias2);

    // 5) Scores: 8 batched NT-GEMMs on raw q, M=2048, N=512, K=128
    score128_kernel<<<dim3(N_TOK / 128, SUB / 128, HEADS * 2), 256, 0, stream>>>(
        q, keys2, bias2, s1, s2);

    // 6) Top-k + softmax
    topk_kernel<<<N_TOK * HEADS / 4, 256, 0, stream>>>(s1, s2, tidx, tw);

    // 7) Weighted gather from values
    gather_kernel<<<N_TOK, 256, 0, stream>>>(values, tidx, tw, rows);

    // 8) Reduce over L=64
    reduce_kernel<<<32, 512, 0, stream>>>(rows, out);
}

// Round 3
// 767.122 us; speedup vs baseline: 1.1705x; 1.0075x over previous
//
#include <hip/hip_runtime.h>
#include <hip/hip_bf16.h>
#include <math.h>

// Problem constants
#define N_TOK   2048      // B*L = 32*64
#define HDIM    512
#define HHALF   256       // H/2
#define QDIM    1024      // 2*H
#define KDIM    256
#define HALF    128
#define HEADS   4
#define KNN     32
#define SUB     512
#define NROWS   8192      // N_TOK * HEADS (batchnorm rows)

// ---------------------------------------------------------------------------
// Generic NT GEMM tile: C[m][n] = sum_k A[m][k] * B[n][k] (+bias, relu)
// 64x64 tile, 256 threads, 4x4 microtile, BK=16.  (used for fc1 only)
// ---------------------------------------------------------------------------
__device__ __forceinline__ void gemm_tile_nt(
    const float* __restrict__ A, int lda,
    const float* __restrict__ B, int ldb,
    float* __restrict__ C, int ldc,
    int K, const float* __restrict__ bias, bool relu,
    int m0, int n0)
{
    __shared__ float As[16][68];
    __shared__ float Bs[16][68];
    int tid = threadIdx.x;
    int tx = tid & 15;        // n-dir
    int ty = tid >> 4;        // m-dir
    int lr = tid >> 2;        // 0..63: row within tile for loads
    int lc = (tid & 3) * 4;   // 0,4,8,12: k within K-tile for loads

    float acc[4][4] = {};

    for (int k0 = 0; k0 < K; k0 += 16) {
        float4 a = *(const float4*)(A + (size_t)(m0 + lr) * lda + k0 + lc);
        float4 b = *(const float4*)(B + (size_t)(n0 + lr) * ldb + k0 + lc);
        As[lc + 0][lr] = a.x; As[lc + 1][lr] = a.y;
        As[lc + 2][lr] = a.z; As[lc + 3][lr] = a.w;
        Bs[lc + 0][lr] = b.x; Bs[lc + 1][lr] = b.y;
        Bs[lc + 2][lr] = b.z; Bs[lc + 3][lr] = b.w;
        __syncthreads();
#pragma unroll
        for (int k = 0; k < 16; ++k) {
            float4 av = *(const float4*)&As[k][ty * 4];
            float4 bv = *(const float4*)&Bs[k][tx * 4];
            acc[0][0] = fmaf(av.x, bv.x, acc[0][0]);
            acc[0][1] = fmaf(av.x, bv.y, acc[0][1]);
            acc[0][2] = fmaf(av.x, bv.z, acc[0][2]);
            acc[0][3] = fmaf(av.x, bv.w, acc[0][3]);
            acc[1][0] = fmaf(av.y, bv.x, acc[1][0]);
            acc[1][1] = fmaf(av.y, bv.y, acc[1][1]);
            acc[1][2] = fmaf(av.y, bv.z, acc[1][2]);
            acc[1][3] = fmaf(av.y, bv.w, acc[1][3]);
            acc[2][0] = fmaf(av.z, bv.x, acc[2][0]);
            acc[2][1] = fmaf(av.z, bv.y, acc[2][1]);
            acc[2][2] = fmaf(av.z, bv.z, acc[2][2]);
            acc[2][3] = fmaf(av.z, bv.w, acc[2][3]);
            acc[3][0] = fmaf(av.w, bv.x, acc[3][0]);
            acc[3][1] = fmaf(av.w, bv.y, acc[3][1]);
            acc[3][2] = fmaf(av.w, bv.z, acc[3][2]);
            acc[3][3] = fmaf(av.w, bv.w, acc[3][3]);
        }
        __syncthreads();
    }

    float4 bb = make_float4(0.f, 0.f, 0.f, 0.f);
    if (bias) {
        bb.x = bias[n0 + tx * 4 + 0];
        bb.y = bias[n0 + tx * 4 + 1];
        bb.z = bias[n0 + tx * 4 + 2];
        bb.w = bias[n0 + tx * 4 + 3];
    }
#pragma unroll
    for (int i = 0; i < 4; ++i) {
        int m = m0 + ty * 4 + i;
        float4 r;
        r.x = acc[i][0] + bb.x;
        r.y = acc[i][1] + bb.y;
        r.z = acc[i][2] + bb.z;
        r.w = acc[i][3] + bb.w;
        if (relu) {
            r.x = fmaxf(r.x, 0.f); r.y = fmaxf(r.y, 0.f);
            r.z = fmaxf(r.z, 0.f); r.w = fmaxf(r.w, 0.f);
        }
        *(float4*)(C + (size_t)m * ldc + n0 + tx * 4) = r;
    }
}

__global__ __launch_bounds__(256) void gemm_nt_kernel(
    const float* __restrict__ A, int lda,
    const float* __restrict__ B, int ldb,
    float* __restrict__ C, int ldc,
    int K, const float* __restrict__ bias, int relu)
{
    gemm_tile_nt(A, lda, B, ldb, C, ldc, K, bias, relu != 0,
                 blockIdx.x * 64, blockIdx.y * 64);
}

// ---------------------------------------------------------------------------
// fc2 + fused batchnorm statistics.
// q = h @ w2^T + b2 (64x64 tiles), plus deterministic per-block column
// sums/sumsq written to pstat[2][32][1024] for bn finalize.
// ---------------------------------------------------------------------------
__global__ __launch_bounds__(256) void fc2_stats_kernel(
    const float* __restrict__ A,   // h: 2048 x 256
    const float* __restrict__ B,   // w2: 1024 x 256
    float* __restrict__ C,         // q: 2048 x 1024
    const float* __restrict__ bias,
    float* __restrict__ pstat)     // 2 * 32 * 1024 floats
{
    __shared__ float As[16][68];
    __shared__ float Bs[16][68];
    int tid = threadIdx.x;
    int tx = tid & 15;
    int ty = tid >> 4;
    int lr = tid >> 2;
    int lc = (tid & 3) * 4;
    int m0 = blockIdx.x * 64;   // token block (0..31)
    int n0 = blockIdx.y * 64;   // q-col block (0..15)

    float acc[4][4] = {};

    for (int k0 = 0; k0 < HHALF; k0 += 16) {
        float4 a = *(const float4*)(A + (size_t)(m0 + lr) * HHALF + k0 + lc);
        float4 b = *(const float4*)(B + (size_t)(n0 + lr) * HHALF + k0 + lc);
        As[lc + 0][lr] = a.x; As[lc + 1][lr] = a.y;
        As[lc + 2][lr] = a.z; As[lc + 3][lr] = a.w;
        Bs[lc + 0][lr] = b.x; Bs[lc + 1][lr] = b.y;
        Bs[lc + 2][lr] = b.z; Bs[lc + 3][lr] = b.w;
        __syncthreads();
#pragma unroll
        for (int k = 0; k < 16; ++k) {
            float4 av = *(const float4*)&As[k][ty * 4];
            float4 bv = *(const float4*)&Bs[k][tx * 4];
            acc[0][0] = fmaf(av.x, bv.x, acc[0][0]);
            acc[0][1] = fmaf(av.x, bv.y, acc[0][1]);
            acc[0][2] = fmaf(av.x, bv.z, acc[0][2]);
            acc[0][3] = fmaf(av.x, bv.w, acc[0][3]);
            acc[1][0] = fmaf(av.y, bv.x, acc[1][0]);
            acc[1][1] = fmaf(av.y, bv.y, acc[1][1]);
            acc[1][2] = fmaf(av.y, bv.z, acc[1][2]);
            acc[1][3] = fmaf(av.y, bv.w, acc[1][3]);
            acc[2][0] = fmaf(av.z, bv.x, acc[2][0]);
            acc[2][1] = fmaf(av.z, bv.y, acc[2][1]);
            acc[2][2] = fmaf(av.z, bv.z, acc[2][2]);
            acc[2][3] = fmaf(av.z, bv.w, acc[2][3]);
            acc[3][0] = fmaf(av.w, bv.x, acc[3][0]);
            acc[3][1] = fmaf(av.w, bv.y, acc[3][1]);
            acc[3][2] = fmaf(av.w, bv.z, acc[3][2]);
            acc[3][3] = fmaf(av.w, bv.w, acc[3][3]);
        }
        __syncthreads();
    }

    float4 bb;
    bb.x = bias[n0 + tx * 4 + 0];
    bb.y = bias[n0 + tx * 4 + 1];
    bb.z = bias[n0 + tx * 4 + 2];
    bb.w = bias[n0 + tx * 4 + 3];
    float4 cs  = make_float4(0.f, 0.f, 0.f, 0.f);
    float4 csq = make_float4(0.f, 0.f, 0.f, 0.f);
#pragma unroll
    for (int i = 0; i < 4; ++i) {
        int m = m0 + ty * 4 + i;
        float4 r;
        r.x = acc[i][0] + bb.x;
        r.y = acc[i][1] + bb.y;
        r.z = acc[i][2] + bb.z;
        r.w = acc[i][3] + bb.w;
        *(float4*)(C + (size_t)m * QDIM + n0 + tx * 4) = r;
        cs.x += r.x; cs.y += r.y; cs.z += r.z; cs.w += r.w;
        csq.x = fmaf(r.x, r.x, csq.x);
        csq.y = fmaf(r.y, r.y, csq.y);
        csq.z = fmaf(r.z, r.z, csq.z);
        csq.w = fmaf(r.w, r.w, csq.w);
    }
    // Deterministic column reduction over ty via LDS (reuse As/Bs).
    __syncthreads();
    As[ty][tx * 4 + 0] = cs.x;  As[ty][tx * 4 + 1] = cs.y;
    As[ty][tx * 4 + 2] = cs.z;  As[ty][tx * 4 + 3] = cs.w;
    Bs[ty][tx * 4 + 0] = csq.x; Bs[ty][tx * 4 + 1] = csq.y;
    Bs[ty][tx * 4 + 2] = csq.z; Bs[ty][tx * 4 + 3] = csq.w;
    __syncthreads();
    if (tid < 64) {
        float s = 0.f, s2 = 0.f;
#pragma unroll
        for (int t = 0; t < 16; ++t) { s += As[t][tid]; s2 += Bs[t][tid]; }
        int mb = blockIdx.x;
        pstat[mb * QDIM + n0 + tid] = s;
        pstat[32 * QDIM + mb * QDIM + n0 + tid] = s2;
    }
}

// ---------------------------------------------------------------------------
// Merged BN-finalize + key folding. Each of the 64 blocks recomputes the
// scale/shift for its half-slice from pstat (256 KB, L2-resident), then
// scales its slice of keys:
//   keys2[z][k][d] = keys[z][k][d] * sc[c],  bias2[z][k] = sum_d sh[c]*key_d
// with c = (z&1)*128 + d.
// ---------------------------------------------------------------------------
__global__ __launch_bounds__(256) void bnprep_kernel(
    const float* __restrict__ pstat,
    const float* __restrict__ gamma, const float* __restrict__ beta,
    const float* __restrict__ keys,
    float* __restrict__ keys2, float* __restrict__ bias2)
{
    int z = blockIdx.x;       // 0..7 (head*2+half)
    int kg = blockIdx.y;      // 0..7
    int half = z & 1;
    int tid = threadIdx.x;

    __shared__ float ssc[HALF];
    __shared__ float ssh[HALF];
    if (tid < HALF) {
        int c = half * HALF + tid;
        float s = 0.f, s2 = 0.f;
        for (int mb = 0; mb < 32; ++mb) {
#pragma unroll
            for (int hd = 0; hd < 4; ++hd) {
                s  += pstat[mb * QDIM + hd * KDIM + c];
                s2 += pstat[32 * QDIM + mb * QDIM + hd * KDIM + c];
            }
        }
        float mean = s * (1.f / (float)NROWS);
        float var = s2 * (1.f / (float)NROWS) - mean * mean;
        float rstd = rsqrtf(var + 1e-5f);
        float sc = rstd * gamma[c];
        ssc[tid] = sc;
        ssh[tid] = beta[c] - mean * sc;
    }
    __syncthreads();

    int r = kg * 64 + (tid >> 2);   // subkey row
    int d0 = (tid & 3) * 32;        // 32 floats per thread
    const float* src = keys  + ((size_t)z * SUB + r) * HALF + d0;
    float*       dst = keys2 + ((size_t)z * SUB + r) * HALF + d0;
    float part = 0.f;
#pragma unroll
    for (int j = 0; j < 32; j += 4) {
        float4 kv = *(const float4*)(src + j);
        float4 scv = *(const float4*)(&ssc[d0 + j]);
        float4 shv = *(const float4*)(&ssh[d0 + j]);
        float4 o;
        o.x = kv.x * scv.x; o.y = kv.y * scv.y;
        o.z = kv.z * scv.z; o.w = kv.w * scv.w;
        part += kv.x * shv.x + kv.y * shv.y + kv.z * shv.z + kv.w * shv.w;
        *(float4*)(dst + j) = o;
    }
    part += __shfl_xor(part, 1);
    part += __shfl_xor(part, 2);
    if ((tid & 3) == 0) bias2[z * SUB + r] = part;
}

// ---------------------------------------------------------------------------
// Score GEMM: 128x128 tile, 8x8 microtile (split halves to kill LDS bank
// conflicts: reads at [tx*4] and [64+tx*4] hit 8 banks 2-way (free) instead
// of [tx*8]'s 4-bank 4-way), BK=16, K=128.
// ---------------------------------------------------------------------------
__global__ __launch_bounds__(256) void score128_kernel(
    const float* __restrict__ q, const float* __restrict__ keys2,
    const float* __restrict__ bias2,
    float* __restrict__ s1, float* __restrict__ s2)
{
    int z = blockIdx.z;
    int hh = z >> 1;
    int half = z & 1;
    const float* A = q + hh * KDIM + half * HALF;        // lda = 1024
    const float* B = keys2 + (size_t)z * SUB * HALF;     // ldb = 128
    float* C = (half ? s2 : s1) + hh * SUB;              // ldc = 2048
    int m0 = blockIdx.x * 128;
    int n0 = blockIdx.y * 128;

    __shared__ float As[16][132];
    __shared__ float Bs[16][132];
    int tid = threadIdx.x;
    int tx = tid & 15;        // n-dir: cols {tx*4+j, 64+tx*4+j}
    int ty = tid >> 4;        // m-dir: rows {ty*4+i, 64+ty*4+i}
    int lr = tid >> 1;        // 0..127: tile row for staging
    int lc = (tid & 1) * 8;   // 0 or 8: k offset for staging

    float acc[8][8] = {};

#pragma unroll 1
    for (int k0 = 0; k0 < HALF; k0 += 16) {
        float4 a0 = *(const float4*)(A + (size_t)(m0 + lr) * QDIM + k0 + lc);
        float4 a1 = *(const float4*)(A + (size_t)(m0 + lr) * QDIM + k0 + lc + 4);
        float4 b0 = *(const float4*)(B + (size_t)(n0 + lr) * HALF + k0 + lc);
        float4 b1 = *(const float4*)(B + (size_t)(n0 + lr) * HALF + k0 + lc + 4);
        As[lc + 0][lr] = a0.x; As[lc + 1][lr] = a0.y;
        As[lc + 2][lr] = a0.z; As[lc + 3][lr] = a0.w;
        As[lc + 4][lr] = a1.x; As[lc + 5][lr] = a1.y;
        As[lc + 6][lr] = a1.z; As[lc + 7][lr] = a1.w;
        Bs[lc + 0][lr] = b0.x; Bs[lc + 1][lr] = b0.y;
        Bs[lc + 2][lr] = b0.z; Bs[lc + 3][lr] = b0.w;
        Bs[lc + 4][lr] = b1.x; Bs[lc + 5][lr] = b1.y;
        Bs[lc + 6][lr] = b1.z; Bs[lc + 7][lr] = b1.w;
        __syncthreads();
#pragma unroll
        for (int k = 0; k < 16; ++k) {
            float4 avA = *(const float4*)&As[k][ty * 4];
            float4 avB = *(const float4*)&As[k][64 + ty * 4];
            float4 bvA = *(const float4*)&Bs[k][tx * 4];
            float4 bvB = *(const float4*)&Bs[k][64 + tx * 4];
            float a8[8] = {avA.x, avA.y, avA.z, avA.w, avB.x, avB.y, avB.z, avB.w};
            float b8[8] = {bvA.x, bvA.y, bvA.z, bvA.w, bvB.x, bvB.y, bvB.z, bvB.w};
#pragma unroll
            for (int i = 0; i < 8; ++i)
#pragma unroll
                for (int j = 0; j < 8; ++j)
                    acc[i][j] = fmaf(a8[i], b8[j], acc[i][j]);
        }
        __syncthreads();
    }

    float4 sbA = *(const float4*)(bias2 + z * SUB + n0 + tx * 4);
    float4 sbB = *(const float4*)(bias2 + z * SUB + n0 + 64 + tx * 4);
#pragma unroll
    for (int i = 0; i < 8; ++i) {
        int m = m0 + ((i < 4) ? (ty * 4 + i) : (64 + ty * 4 + (i - 4)));
        float4 r0, r1;
        r0.x = acc[i][0] + sbA.x; r0.y = acc[i][1] + sbA.y;
        r0.z = acc[i][2] + sbA.z; r0.w = acc[i][3] + sbA.w;
        r1.x = acc[i][4] + sbB.x; r1.y = acc[i][5] + sbB.y;
        r1.z = acc[i][6] + sbB.z; r1.w = acc[i][7] + sbB.w;
        *(float4*)(C + (size_t)m * (HEADS * SUB) + n0 + tx * 4) = r0;
        *(float4*)(C + (size_t)m * (HEADS * SUB) + n0 + 64 + tx * 4) = r1;
    }
}

// ---------------------------------------------------------------------------
// Top-k via ballot-popcount radix select with exact-count early exit.
// 4 tasks per 256-thread block; each wave owns one (n, head) task.
// ---------------------------------------------------------------------------
__device__ __forceinline__ unsigned fmap(float f) {
    unsigned u = __float_as_uint(f);
    return (u & 0x80000000u) ? ~u : (u | 0x80000000u);
}

__device__ __forceinline__ int mbcnt64(unsigned long long m) {
    return __builtin_amdgcn_mbcnt_hi((unsigned)(m >> 32),
           __builtin_amdgcn_mbcnt_lo((unsigned)(m & 0xffffffffu), 0));
}

__global__ __launch_bounds__(256) void topk_kernel(
    const float* __restrict__ s1, const float* __restrict__ s2,
    int* __restrict__ out_idx, float* __restrict__ out_w)
{
    int w = threadIdx.x >> 6;            // wave within block: task slot
    int lane = threadIdx.x & 63;
    int task = blockIdx.x * 4 + w;       // n*HEADS + h

    __shared__ float ts1[4][KNN]; __shared__ int ti1[4][KNN];
    __shared__ float ts2[4][KNN]; __shared__ int ti2[4][KNN];
    __shared__ float scv[4][KNN]; __shared__ int scp[4][KNN];

    // Stage 1: top-32 of 512, twice
    for (int src = 0; src < 2; ++src) {
        const float* base = (src ? s2 : s1) + (size_t)task * SUB;
        float v[8]; unsigned u[8];
#pragma unroll
        for (int i = 0; i < 8; ++i) {
            v[i] = base[lane + 64 * i];
            u[i] = fmap(v[i]);
        }
        unsigned t = 0u;
        for (int bit = 31; bit >= 0; --bit) {
            unsigned cand = t | (1u << bit);
            int cnt = 0;
#pragma unroll
            for (int i = 0; i < 8; ++i)
                cnt += __popcll(__ballot(u[i] >= cand));
            if (cnt == KNN) { t = cand; break; }   // exact set found
            if (cnt > KNN) t = cand;
        }
        float* tsv = src ? ts2[w] : ts1[w];
        int*   tsi = src ? ti2[w] : ti1[w];
        int pbase = 0;
#pragma unroll
        for (int i = 0; i < 8; ++i) {
            unsigned long long m = __ballot(u[i] >= t);
            if (u[i] >= t) {
                int pos = pbase + mbcnt64(m);
                if (pos < KNN) { tsv[pos] = v[i]; tsi[pos] = lane + 64 * i; }
            }
            pbase += __popcll(m);
        }
    }
    __syncthreads();

    // Stage 2: top-32 of the 1024 pairwise sums
    float cv[16]; unsigned cu[16];
#pragma unroll
    for (int i = 0; i < 16; ++i) {
        int p = lane + 64 * i;
        cv[i] = ts1[w][p >> 5] + ts2[w][p & 31];
        cu[i] = fmap(cv[i]);
    }
    unsigned t2 = 0u;
    for (int bit = 31; bit >= 0; --bit) {
        unsigned cand = t2 | (1u << bit);
        int cnt = 0;
#pragma unroll
        for (int i = 0; i < 16; ++i)
            cnt += __popcll(__ballot(cu[i] >= cand));
        if (cnt == KNN) { t2 = cand; break; }
        if (cnt > KNN) t2 = cand;
    }
    int pbase = 0;
#pragma unroll
    for (int i = 0; i < 16; ++i) {
        unsigned long long m = __ballot(cu[i] >= t2);
        if (cu[i] >= t2) {
            int pos = pbase + mbcnt64(m);
            if (pos < KNN) { scv[w][pos] = cv[i]; scp[w][pos] = lane + 64 * i; }
        }
        pbase += __popcll(m);
    }
    __syncthreads();

    // Softmax over the 32 winners
    float x = (lane < KNN) ? scv[w][lane] : -3.0e38f;
    float mx = x;
#pragma unroll
    for (int off = 32; off; off >>= 1) mx = fmaxf(mx, __shfl_xor(mx, off));
    float e = (lane < KNN) ? expf(x - mx) : 0.f;
    float ssum = e;
#pragma unroll
    for (int off = 32; off; off >>= 1) ssum += __shfl_xor(ssum, off);

    if (lane < KNN) {
        int p = scp[w][lane];
        int i = p >> 5, j = p & 31;
        int gidx = ti1[w][i] * SUB + ti2[w][j];
        int n = task >> 2, h = task & 3;
        out_idx[n * (HEADS * KNN) + h * KNN + lane] = gidx;
        out_w[n * (HEADS * KNN) + h * KNN + lane] = e / ssum;
    }
}

// ---------------------------------------------------------------------------
// Gather, 2-way k-split: rowsp[ks][n][:] = sum_{k in [ks*64, ks*64+64)}
// w[n][k] * values[idx[n][k]][:].  Doubles block-level concurrency (latency
// probe) at the cost of one extra 4 MB partial buffer; deterministic (no
// atomics; reduce sums partials in fixed order).
// ---------------------------------------------------------------------------
__global__ __launch_bounds__(256) void gather_kernel(
    const float* __restrict__ values, const int* __restrict__ idx,
    const float* __restrict__ w, float* __restrict__ rowsp)
{
    int n = blockIdx.x;
    int ks = blockIdx.y;      // 0/1: which 64 of the 128 selected rows
    int tid = threadIdx.x;
    int pair = tid >> 7;      // 0/1: k-parity within this half
    int c4 = tid & 127;       // float4 column
    __shared__ int sidx[64];
    __shared__ float sw[64];
    __shared__ float4 tmp[128];
    if (tid < 64) {
        sidx[tid] = idx[n * (HEADS * KNN) + ks * 64 + tid];
        sw[tid] = w[n * (HEADS * KNN) + ks * 64 + tid];
    }
    __syncthreads();
    const float4* vv = (const float4*)values;
    float4 acc = make_float4(0.f, 0.f, 0.f, 0.f);
#pragma unroll 16
    for (int k = pair; k < 64; k += 2) {
        float4 v = vv[(size_t)sidx[k] * (HDIM / 4) + c4];
        float wk = sw[k];
        acc.x = fmaf(wk, v.x, acc.x);
        acc.y = fmaf(wk, v.y, acc.y);
        acc.z = fmaf(wk, v.z, acc.z);
        acc.w = fmaf(wk, v.w, acc.w);
    }
    if (pair) tmp[c4] = acc;
    __syncthreads();
    if (!pair) {
        float4 o = tmp[c4];
        acc.x += o.x; acc.y += o.y; acc.z += o.z; acc.w += o.w;
        ((float4*)rowsp)[((size_t)ks * N_TOK + n) * (HDIM / 4) + c4] = acc;
    }
}

// out[b][c] = sum_l (rowsp[0][b*64+l][c] + rowsp[1][b*64+l][c])
__global__ __launch_bounds__(512) void reduce_kernel(
    const float* __restrict__ rowsp, float* __restrict__ out)
{
    int b = blockIdx.x;
    int c = threadIdx.x;
    float s = 0.f;
    for (int l = 0; l < 64; ++l) {
        s += rowsp[(size_t)(b * 64 + l) * HDIM + c];
        s += rowsp[(size_t)(N_TOK + b * 64 + l) * HDIM + c];
    }
    out[b * HDIM + c] = s;
}

// ---------------------------------------------------------------------------
extern "C" void kernel_launch(void* const* d_in, const int* in_sizes, int n_in,
                              void* d_out, int out_size, void* d_ws, size_t ws_size,
                              hipStream_t stream)
{
    const float* x      = (const float*)d_in[0];  // (32,64,512)
    const float* w1     = (const float*)d_in[1];  // (256,512)
    const float* b1     = (const float*)d_in[2];  // (256)
    const float* w2     = (const float*)d_in[3];  // (1024,256)
    const float* b2     = (const float*)d_in[4];  // (1024)
    const float* gamma  = (const float*)d_in[5];  // (256)
    const float* beta   = (const float*)d_in[6];  // (256)
    const float* keys   = (const float*)d_in[7];  // (4,2,512,128)
    const float* values = (const float*)d_in[8];  // (262144,512)
    float* out = (float*)d_out;                   // (32,512)

    // Workspace layout (floats). Total ~57 MB.
    float* ws = (float*)d_ws;
    float* h     = ws;                          // 2048*256
    float* q     = h + N_TOK * HHALF;           // 2048*1024
    float* pstat = q + N_TOK * QDIM;            // 2*32*1024
    float* keys2 = pstat + 2 * 32 * QDIM;       // 8*512*128
    float* bias2 = keys2 + 8 * SUB * HALF;      // 8*512
    float* s1    = bias2 + 8 * SUB;             // 2048*4*512
    float* s2    = s1 + (size_t)N_TOK * HEADS * SUB;
    int*   tidx  = (int*)(s2 + (size_t)N_TOK * HEADS * SUB);
    float* tw    = (float*)(tidx + N_TOK * HEADS * KNN);
    float* rowsp = tw + N_TOK * HEADS * KNN;    // 2*2048*512

    // 1) h = relu(x @ w1^T + b1): M=2048, N=256, K=512
    gemm_nt_kernel<<<dim3(N_TOK / 64, HHALF / 64), 256, 0, stream>>>(
        x, HDIM, w1, HDIM, h, HHALF, HDIM, b1, 1);

    // 2) q = h @ w2^T + b2, fused column stats
    fc2_stats_kernel<<<dim3(N_TOK / 64, QDIM / 64), 256, 0, stream>>>(
        h, w2, q, b2, pstat);

    // 3) BN finalize + fold into keys (merged)
    bnprep_kernel<<<dim3(8, 8), 256, 0, stream>>>(
        pstat, gamma, beta, keys, keys2, bias2);

    // 4) Scores: 8 batched NT-GEMMs on raw q, M=2048, N=512, K=128
    score128_kernel<<<dim3(N_TOK / 128, SUB / 128, HEADS * 2), 256, 0, stream>>>(
        q, keys2, bias2, s1, s2);

    // 5) Top-k + softmax
    topk_kernel<<<N_TOK * HEADS / 4, 256, 0, stream>>>(s1, s2, tidx, tw);

    // 6) Weighted gather from values (2-way k-split)
    gather_kernel<<<dim3(N_TOK, 2), 256, 0, stream>>>(values, tidx, tw, rowsp);

    // 7) Reduce over L=64 and the 2 partials
    reduce_kernel<<<32, 512, 0, stream>>>(rowsp, out);
}